// Round 1
// baseline (1349.111 us; speedup 1.0000x reference)
//
#include <hip/hip_runtime.h>
#include <math.h>

#define EMBED 768
#define HIDDEN 1536
#define H2 3072
#define STATE 16
#define RANK 48
#define BSZ 4
#define LEN 512
#define BL (BSZ*LEN)   // 2048

__device__ __forceinline__ float silu_f(float x) { return x / (1.0f + expf(-x)); }

// ---------------------------------------------------------------------------
// Generic 64x64 tiled f32 GEMM: C[M,N] = A[M,K] @ B[K,N]; M,N %64==0, K%16==0
// ---------------------------------------------------------------------------
__global__ __launch_bounds__(256)
void gemm64_f32(const float* __restrict__ A, const float* __restrict__ B,
                float* __restrict__ C, int M, int N, int Kd) {
  __shared__ float As[16][65];
  __shared__ float Bs[16][65];
  const int bm = blockIdx.y * 64, bn = blockIdx.x * 64;
  const int tid = threadIdx.x;
  const int tr = tid >> 4, tc = tid & 15;
  float acc[4][4] = {};
  for (int k0 = 0; k0 < Kd; k0 += 16) {
#pragma unroll
    for (int i = 0; i < 4; ++i) {
      int idx = tid + i * 256;              // 1024 elems each matrix
      int m = idx >> 4, k = idx & 15;
      As[k][m] = A[(size_t)(bm + m) * Kd + k0 + k];
      int kk = idx >> 6, n = idx & 63;
      Bs[kk][n] = B[(size_t)(k0 + kk) * N + bn + n];
    }
    __syncthreads();
#pragma unroll
    for (int k = 0; k < 16; ++k) {
      float a[4], b[4];
#pragma unroll
      for (int i = 0; i < 4; ++i) a[i] = As[k][tr * 4 + i];
#pragma unroll
      for (int j = 0; j < 4; ++j) b[j] = Bs[k][tc * 4 + j];
#pragma unroll
      for (int i = 0; i < 4; ++i)
#pragma unroll
        for (int j = 0; j < 4; ++j) acc[i][j] = fmaf(a[i], b[j], acc[i][j]);
    }
    __syncthreads();
  }
#pragma unroll
  for (int i = 0; i < 4; ++i)
#pragma unroll
    for (int j = 0; j < 4; ++j)
      C[(size_t)(bm + tr * 4 + i) * N + bn + tc * 4 + j] = acc[i][j];
}

// ---------------------------------------------------------------------------
// Conv-as-shifted-GEMM:
//   s[b,l,h] = silu(b_conv[l] + sum_{k<4, c<512} stream[b,c,h+k-3] * Wc[k,c,l])
//   stream[b,c,w] = xp[(b*LEN+c)*H2 + w]   (first half of xp rows)
// Block computes 64(h) x 64(l) for one b; reduction over c in chunks of 16.
// ---------------------------------------------------------------------------
__global__ __launch_bounds__(256)
void conv_gemm(const float* __restrict__ xp, const float* __restrict__ Wc,
               const float* __restrict__ bconv, float* __restrict__ s) {
  __shared__ float Ss[16][68];        // Ss[c][d] = stream[b, c0+c, h0-3+d], d<67
  __shared__ float Wt[4][16][64];     // Wt[k][c][j] = Wc[k, c0+c, l0+j]
  const int h0 = blockIdx.x * 64;
  const int l0 = blockIdx.y * 64;
  const int b  = blockIdx.z;
  const int tid = threadIdx.x;
  const int tr = tid >> 4;            // l sub-tile
  const int tc = tid & 15;            // h sub-tile
  float acc[4][4] = {};               // [i: l][j: h]
  for (int c0 = 0; c0 < LEN; c0 += 16) {
    for (int i = tid; i < 16 * 68; i += 256) {
      int c = i / 68, d = i % 68;
      int w = h0 - 3 + d;
      float v = 0.f;
      if (d < 67 && w >= 0 && w < HIDDEN)
        v = xp[(size_t)(b * LEN + c0 + c) * H2 + w];
      Ss[c][d] = v;
    }
#pragma unroll
    for (int i = 0; i < 16; ++i) {
      int idx = tid + i * 256;        // 4096 elems
      int k = idx >> 10;
      int c = (idx >> 6) & 15;
      int j = idx & 63;
      Wt[k][c][j] = Wc[(size_t)(k * LEN + c0 + c) * HIDDEN + l0 + j];
    }
    __syncthreads();
#pragma unroll 4
    for (int c = 0; c < 16; ++c) {
#pragma unroll
      for (int k = 0; k < 4; ++k) {
        float a[4], bb[4];
#pragma unroll
        for (int j = 0; j < 4; ++j) a[j] = Ss[c][tc * 4 + j + k];
#pragma unroll
        for (int i = 0; i < 4; ++i) bb[i] = Wt[k][c][tr * 4 + i];
#pragma unroll
        for (int i = 0; i < 4; ++i)
#pragma unroll
          for (int j = 0; j < 4; ++j) acc[i][j] = fmaf(bb[i], a[j], acc[i][j]);
      }
    }
    __syncthreads();
  }
#pragma unroll
  for (int i = 0; i < 4; ++i) {
    int l = l0 + tr * 4 + i;
    float bc = bconv[l];
#pragma unroll
    for (int j = 0; j < 4; ++j) {
      int h = h0 + tc * 4 + j;
      s[(size_t)(b * LEN + l) * HIDDEN + h] = silu_f(acc[i][j] + bc);
    }
  }
}

// ---------------------------------------------------------------------------
// BCD = s @ W_param : (2048,1536)@(1536,80). Block: 16 rows x 80 cols.
// ---------------------------------------------------------------------------
__global__ __launch_bounds__(256)
void gemm_bcd(const float* __restrict__ s, const float* __restrict__ Wp,
              float* __restrict__ BCD) {
  __shared__ float st[16][65];
  __shared__ float wt[64][80];
  const int t0 = blockIdx.x * 16;
  const int tid = threadIdx.x;
  const int tr = tid >> 4, tc = tid & 15;
  float acc[5] = {};
  for (int r0 = 0; r0 < HIDDEN; r0 += 64) {
#pragma unroll
    for (int i = 0; i < 4; ++i) {
      int idx = tid + i * 256;
      int row = idx >> 6, rr = idx & 63;
      st[row][rr] = s[(size_t)(t0 + row) * HIDDEN + r0 + rr];
    }
#pragma unroll
    for (int i = 0; i < 20; ++i) {
      int idx = tid + i * 256;        // 5120 elems exactly
      int r = idx / 80, j = idx % 80;
      wt[r][j] = Wp[(size_t)(r0 + r) * 80 + j];
    }
    __syncthreads();
#pragma unroll 8
    for (int r = 0; r < 64; ++r) {
      float sv = st[tr][r];
#pragma unroll
      for (int q = 0; q < 5; ++q)
        acc[q] = fmaf(sv, wt[r][tc + 16 * q], acc[q]);
    }
    __syncthreads();
  }
#pragma unroll
  for (int q = 0; q < 5; ++q)
    BCD[(size_t)(t0 + tr) * 80 + tc + 16 * q] = acc[q];
}

// ---------------------------------------------------------------------------
// delta = softplus(delta_r @ W_delta + b_delta) : K=48.
// Block: 256 h-columns x 8 t-rows.
// ---------------------------------------------------------------------------
__global__ __launch_bounds__(256)
void gemm_delta(const float* __restrict__ BCD, const float* __restrict__ Wd,
                const float* __restrict__ bd, float* __restrict__ delta) {
  __shared__ float dr[8][48];
  const int h = blockIdx.x * 256 + threadIdx.x;
  const int t0 = blockIdx.y * 8;
  for (int i = threadIdx.x; i < 8 * 48; i += 256) {
    int q = i / 48, r = i % 48;
    dr[q][r] = BCD[(size_t)(t0 + q) * 80 + r];
  }
  __syncthreads();
  float acc[8];
  float bdh = bd[h];
#pragma unroll
  for (int q = 0; q < 8; ++q) acc[q] = bdh;
  for (int r = 0; r < 48; ++r) {
    float w = Wd[(size_t)r * HIDDEN + h];
#pragma unroll
    for (int q = 0; q < 8; ++q) acc[q] = fmaf(dr[q][r], w, acc[q]);
  }
#pragma unroll
  for (int q = 0; q < 8; ++q) {
    float x = acc[q];
    float sp = fmaxf(x, 0.f) + log1pf(expf(-fabsf(x)));   // stable softplus
    delta[(size_t)(t0 + q) * HIDDEN + h] = sp;
  }
}

// ---------------------------------------------------------------------------
// Fused selective scan + x*D + *silu(res).  4 lanes per (b,d), 4 states/lane.
// z[b,l,d] = (scan_y + s*D[d]) * silu(res[b,l,d])
// ---------------------------------------------------------------------------
__global__ __launch_bounds__(256)
void scan_kernel(const float* __restrict__ s, const float* __restrict__ delta,
                 const float* __restrict__ BCD, const float* __restrict__ logA,
                 const float* __restrict__ Dp, const float* __restrict__ xp,
                 float* __restrict__ z) {
  int g = blockIdx.x * 256 + threadIdx.x;
  int sub = g & 3;
  int pair = g >> 2;
  int b = pair / HIDDEN;
  int d = pair % HIDDEN;
  float An[4];
#pragma unroll
  for (int j = 0; j < 4; ++j) An[j] = -expf(logA[d * STATE + sub * 4 + j]);
  float Dv = Dp[d];
  float h0 = 0.f, h1 = 0.f, h2 = 0.f, h3 = 0.f;
  for (int l = 0; l < LEN; ++l) {
    size_t row = (size_t)b * LEN + l;
    float dt = delta[row * HIDDEN + d];
    float xt = s[row * HIDDEN + d];
    const float4 Bv = *reinterpret_cast<const float4*>(&BCD[row * 80 + RANK + sub * 4]);
    const float4 Cv = *reinterpret_cast<const float4*>(&BCD[row * 80 + RANK + STATE + sub * 4]);
    float dBx = dt * xt;
    float y = 0.f;
    h0 = expf(dt * An[0]) * h0 + dBx * Bv.x;  y += h0 * Cv.x;
    h1 = expf(dt * An[1]) * h1 + dBx * Bv.y;  y += h1 * Cv.y;
    h2 = expf(dt * An[2]) * h2 + dBx * Bv.z;  y += h2 * Cv.z;
    h3 = expf(dt * An[3]) * h3 + dBx * Bv.w;  y += h3 * Cv.w;
    y += __shfl_xor(y, 1);
    y += __shfl_xor(y, 2);
    if (sub == 0) {
      float res = xp[row * H2 + HIDDEN + d];
      z[row * HIDDEN + d] = (y + xt * Dv) * silu_f(res);
    }
  }
}

// ---------------------------------------------------------------------------
extern "C" void kernel_launch(void* const* d_in, const int* in_sizes, int n_in,
                              void* d_out, int out_size, void* d_ws, size_t ws_size,
                              hipStream_t stream) {
  const float* inp     = (const float*)d_in[0];
  const float* W_in    = (const float*)d_in[1];
  const float* W_conv  = (const float*)d_in[2];
  const float* b_conv  = (const float*)d_in[3];
  const float* W_param = (const float*)d_in[4];
  const float* W_delta = (const float*)d_in[5];
  const float* b_delta = (const float*)d_in[6];
  const float* log_A   = (const float*)d_in[7];
  const float* Dp      = (const float*)d_in[8];
  const float* W_out   = (const float*)d_in[9];
  float* out = (float*)d_out;

  // workspace layout (f32): 63.6 MB total
  float* xp    = (float*)d_ws;                    // 2048*3072
  float* s     = xp + (size_t)BL * H2;            // 2048*1536
  float* BCD   = s + (size_t)BL * HIDDEN;         // 2048*80
  float* delta = BCD + (size_t)BL * 80;           // 2048*1536
  float* z     = delta + (size_t)BL * HIDDEN;     // 2048*1536

  // 1) xp = inputs @ W_in
  gemm64_f32<<<dim3(H2 / 64, BL / 64), 256, 0, stream>>>(inp, W_in, xp, BL, H2, EMBED);
  // 2) conv-as-GEMM + bias + SiLU -> s[b,l,h]
  conv_gemm<<<dim3(HIDDEN / 64, LEN / 64, BSZ), 256, 0, stream>>>(xp, W_conv, b_conv, s);
  // 3) BCD = s @ W_param
  gemm_bcd<<<BL / 16, 256, 0, stream>>>(s, W_param, BCD);
  // 4) delta = softplus(delta_r @ W_delta + b_delta)
  gemm_delta<<<dim3(HIDDEN / 256, BL / 8), 256, 0, stream>>>(BCD, W_delta, b_delta, delta);
  // 5) fused selective scan -> z = (y + s*D) * silu(res)
  scan_kernel<<<(BSZ * HIDDEN * 4) / 256, 256, 0, stream>>>(s, delta, BCD, log_A, Dp, xp, z);
  // 6) out = z @ W_out
  gemm64_f32<<<dim3(EMBED / 64, BL / 64), 256, 0, stream>>>(z, W_out, out, BL, EMBED, HIDDEN);
}